// Round 7
// baseline (411.570 us; speedup 1.0000x reference)
//
#include <hip/hip_runtime.h>
#include <hip/hip_bf16.h>

// Problem constants (fixed by reference file)
#define EMBED    256
#define HEADS    8
#define LEVELS   4
#define POINTS   4
#define HEAD_DIM 32
#define BS       8
#define NQ       900
#define NV       13294          // 100*100 + 50*50 + 25*25 + 13*13
#define MV       (BS*NV)        // 106352 = 6647*16
#define MQ       (BS*NQ)        // 7200   = 450*16
#define NQOUT    384            // 256 offset cols + 128 attn cols

typedef float  f32x4  __attribute__((ext_vector_type(4)));
typedef __bf16 bf16x8 __attribute__((ext_vector_type(8)));
typedef unsigned short ushort8  __attribute__((ext_vector_type(8)));
typedef unsigned short ushort4v __attribute__((ext_vector_type(4)));

__device__ __forceinline__ unsigned short f2bf(float f) {
    unsigned u = __builtin_bit_cast(unsigned, f);
    u += 0x7FFFu + ((u >> 16) & 1u);          // RNE
    return (unsigned short)(u >> 16);
}
__device__ __forceinline__ float bf2f(unsigned short h) {
    unsigned u = ((unsigned)h) << 16;
    return __builtin_bit_cast(float, u);
}

// ---------------------------------------------------------------------------
// Prep: transpose + cast weights to bf16 (B^T layout: [n][k], k contiguous)
// ---------------------------------------------------------------------------
__global__ __launch_bounds__(256) void prep_kernel(
    const float* __restrict__ Wv,  const float* __restrict__ Woff,
    const float* __restrict__ Wattn, const float* __restrict__ Wout,
    const float* __restrict__ boff, const float* __restrict__ battn,
    unsigned short* __restrict__ WtV, unsigned short* __restrict__ WtQ,
    unsigned short* __restrict__ WtO, float* __restrict__ biasQ)
{
    int n = blockIdx.x;      // 0..383
    int k = threadIdx.x;     // 0..255
    if (n < 256) {
        WtV[n * 256 + k] = f2bf(Wv [k * 256 + n]);
        WtO[n * 256 + k] = f2bf(Wout[k * 256 + n]);
        WtQ[n * 256 + k] = f2bf(Woff[k * 256 + n]);
    } else {
        int j = n - 256;
        WtQ[n * 256 + k] = f2bf(Wattn[k * 128 + j]);
    }
    if (k == 0) biasQ[n] = (n < 256) ? boff[n] : battn[n - 256];
}

// ---------------------------------------------------------------------------
// LDS-weight streaming GEMM (K=256) — EXACT R0 body. Session facts:
//  R0  <2,4> 512thr 67.6KB (1 blk/CU, 8 waves):  V-GEMM 85us, FETCH=1x. BEST.
//  R3  <2,4> 512thr 64.0KB (2 blk/CU, 16 waves): 190us, FETCH=4x — the 2nd
//      co-resident block halves per-CU cache share; colset re-reads all miss.
//  R1/R2: 16 waves via y/colset duplication: 190-200us, FETCH 3.7-5x.
//  R4/R6: 1024thr variants with big per-wave arrays: VGPR spill (hipcc
//      heuristic targets 8 waves/EU -> 64 VGPR unless told otherwise).
// A (108.9MB) is L3-resident, so FETCH here is L2-fill (L3-served) latency
// exposure, not HBM. The cost law: dirty FETCH <=> ~190us; clean <=> 85us.
// ---------------------------------------------------------------------------
#define WLDK 264

template <int COLSETS, int PAR, bool OUT_BF16, bool ADD_ID>
__global__ __launch_bounds__(COLSETS * PAR * 64)
void gemm_ldsw(const float* __restrict__ A,
               const unsigned short* __restrict__ Bt,   // [Ntot][256] bf16
               const float* __restrict__ bias,          // [Ntot]
               const float* __restrict__ Ident,         // [M][Ntot] or null
               void* __restrict__ Cv, int M, int Ntot)
{
    constexpr int NC   = COLSETS * 64;     // cols per block
    constexpr int NTHR = COLSETS * PAR * 64;
    const int n0g = blockIdx.y * NC;
    __shared__ unsigned short Ws[NC * WLDK];

    const int tid = threadIdx.x;
    #pragma unroll
    for (int i = 0; i < (NC * 32) / NTHR; ++i) {        // vec8 tiles
        int flat = i * NTHR + tid;                      // ushort8 index
        int row = flat >> 5, col = (flat & 31) * 8;     // 32 vec8 per row
        *(ushort8*)&Ws[row * WLDK + col] =
            *(const ushort8*)(Bt + (size_t)(n0g + row) * 256 + col);
    }
    __syncthreads();                                    // the only barrier

    const int wave = tid >> 6, lane = tid & 63;
    const int colset = wave % COLSETS, parity = wave / COLSETS;
    const int lrow = lane & 15, kq = lane >> 4;
    const int n0 = colset * 64;

    f32x4 bj[4];
    #pragma unroll
    for (int j = 0; j < 4; ++j)
        bj[j] = *(const f32x4*)(bias + n0g + n0 + j * 16 + kq * 4);

    const int NS    = M / 16;
    const int chunk = (NS + gridDim.x - 1) / gridDim.x;
    const int send  = min(NS, blockIdx.x * chunk + chunk);
    int s = blockIdx.x * chunk + parity;
    if (s >= send) return;

    auto loadHalf = [&](f32x4 (&b)[8], int ss, int h) {
        const float* ab = A + (size_t)(ss * 16 + lrow) * 256 + h * 128 + kq * 8;
        #pragma unroll
        for (int c = 0; c < 4; ++c) {
            b[2 * c]     = *(const f32x4*)(ab + c * 32);
            b[2 * c + 1] = *(const f32x4*)(ab + c * 32 + 4);
        }
    };
    auto computeHalf = [&](f32x4 (&b)[8], int h, f32x4 (&acc)[4]) {
        #pragma unroll
        for (int c = 0; c < 4; ++c) {
            ushort8 vb;
            #pragma unroll
            for (int e = 0; e < 4; ++e) {
                vb[e]     = f2bf(b[2 * c][e]);
                vb[4 + e] = f2bf(b[2 * c + 1][e]);
            }
            bf16x8 vf = __builtin_bit_cast(bf16x8, vb);
            #pragma unroll
            for (int j = 0; j < 4; ++j) {
                bf16x8 wf = *(const bf16x8*)
                    &Ws[(n0 + j * 16 + lrow) * WLDK + h * 128 + c * 32 + kq * 8];
                acc[j] = __builtin_amdgcn_mfma_f32_16x16x32_bf16(wf, vf, acc[j], 0, 0, 0);
            }
        }
    };

    f32x4 b0[8], b1[8];
    loadHalf(b0, s, 0);
    while (true) {
        loadHalf(b1, s, 1);
        f32x4 acc[4];
        #pragma unroll
        for (int j = 0; j < 4; ++j) acc[j] = (f32x4)0.f;
        computeHalf(b0, 0, acc);            // waits only on b0
        const int sn = s + PAR;
        const bool more = sn < send;
        if (more) loadHalf(b0, sn, 0);      // in flight during computeHalf(b1)
        computeHalf(b1, 1, acc);

        const size_t crow = (size_t)(s * 16 + lrow) * Ntot + n0g + n0 + kq * 4;
        #pragma unroll
        for (int j = 0; j < 4; ++j) {
            f32x4 r = acc[j] + bj[j];
            if (ADD_ID)
                r += *(const f32x4*)(Ident + crow + j * 16);
            if (OUT_BF16) {
                ushort4v o;
                #pragma unroll
                for (int e = 0; e < 4; ++e) o[e] = f2bf(r[e]);
                *(ushort4v*)((unsigned short*)Cv + crow + j * 16) = o;
            } else {
                *(f32x4*)((float*)Cv + crow + j * 16) = r;
            }
        }
        if (!more) break;
        s = sn;
    }
}

// ---------------------------------------------------------------------------
// R7's single experiment: the SAME body as gemm_ldsw, but 16 waves in ONE
// exclusive block (1024 thr, 67.6KB padded LDS > 64KB => no pairing), i.e.
// <COLSETS=2, PAR=8>. This is the one untested cell: 16 waves/CU with R0's
// exact sharing pattern (2-way colset within one block) and R0's exclusive
// residency. __launch_bounds__(1024, 4) pins the allocator to 4 waves/EU =
// 128-VGPR budget, closing R4's 64-VGPR-heuristic spill trap (body needs
// ~124, proven at 512thr).
// ---------------------------------------------------------------------------
template <int COLSETS, int PAR, bool OUT_BF16, bool ADD_ID>
__global__ __launch_bounds__(COLSETS * PAR * 64, 4)
void gemm_ldsw16(const float* __restrict__ A,
                 const unsigned short* __restrict__ Bt,   // [Ntot][256] bf16
                 const float* __restrict__ bias,          // [Ntot]
                 const float* __restrict__ Ident,         // [M][Ntot] or null
                 void* __restrict__ Cv, int M, int Ntot)
{
    constexpr int NC   = COLSETS * 64;
    constexpr int NTHR = COLSETS * PAR * 64;
    const int n0g = blockIdx.y * NC;
    __shared__ unsigned short Ws[NC * WLDK];

    const int tid = threadIdx.x;
    #pragma unroll
    for (int i = 0; i < (NC * 32) / NTHR; ++i) {
        int flat = i * NTHR + tid;
        int row = flat >> 5, col = (flat & 31) * 8;
        *(ushort8*)&Ws[row * WLDK + col] =
            *(const ushort8*)(Bt + (size_t)(n0g + row) * 256 + col);
    }
    __syncthreads();

    const int wave = tid >> 6, lane = tid & 63;
    const int colset = wave % COLSETS, parity = wave / COLSETS;
    const int lrow = lane & 15, kq = lane >> 4;
    const int n0 = colset * 64;

    f32x4 bj[4];
    #pragma unroll
    for (int j = 0; j < 4; ++j)
        bj[j] = *(const f32x4*)(bias + n0g + n0 + j * 16 + kq * 4);

    const int NS    = M / 16;
    const int chunk = (NS + gridDim.x - 1) / gridDim.x;
    const int send  = min(NS, blockIdx.x * chunk + chunk);
    int s = blockIdx.x * chunk + parity;
    if (s >= send) return;

    auto loadHalf = [&](f32x4 (&b)[8], int ss, int h) {
        const float* ab = A + (size_t)(ss * 16 + lrow) * 256 + h * 128 + kq * 8;
        #pragma unroll
        for (int c = 0; c < 4; ++c) {
            b[2 * c]     = *(const f32x4*)(ab + c * 32);
            b[2 * c + 1] = *(const f32x4*)(ab + c * 32 + 4);
        }
    };
    auto computeHalf = [&](f32x4 (&b)[8], int h, f32x4 (&acc)[4]) {
        #pragma unroll
        for (int c = 0; c < 4; ++c) {
            ushort8 vb;
            #pragma unroll
            for (int e = 0; e < 4; ++e) {
                vb[e]     = f2bf(b[2 * c][e]);
                vb[4 + e] = f2bf(b[2 * c + 1][e]);
            }
            bf16x8 vf = __builtin_bit_cast(bf16x8, vb);
            #pragma unroll
            for (int j = 0; j < 4; ++j) {
                bf16x8 wf = *(const bf16x8*)
                    &Ws[(n0 + j * 16 + lrow) * WLDK + h * 128 + c * 32 + kq * 8];
                acc[j] = __builtin_amdgcn_mfma_f32_16x16x32_bf16(wf, vf, acc[j], 0, 0, 0);
            }
        }
    };

    f32x4 b0[8], b1[8];
    loadHalf(b0, s, 0);
    while (true) {
        loadHalf(b1, s, 1);
        f32x4 acc[4];
        #pragma unroll
        for (int j = 0; j < 4; ++j) acc[j] = (f32x4)0.f;
        computeHalf(b0, 0, acc);
        const int sn = s + PAR;
        const bool more = sn < send;
        if (more) loadHalf(b0, sn, 0);
        computeHalf(b1, 1, acc);

        const size_t crow = (size_t)(s * 16 + lrow) * Ntot + n0g + n0 + kq * 4;
        #pragma unroll
        for (int j = 0; j < 4; ++j) {
            f32x4 r = acc[j] + bj[j];
            if (ADD_ID)
                r += *(const f32x4*)(Ident + crow + j * 16);
            if (OUT_BF16) {
                ushort4v o;
                #pragma unroll
                for (int e = 0; e < 4; ++e) o[e] = f2bf(r[e]);
                *(ushort4v*)((unsigned short*)Cv + crow + j * 16) = o;
            } else {
                *(f32x4*)((float*)Cv + crow + j * 16) = r;
            }
        }
        if (!more) break;
        s = sn;
    }
}

// ---------------------------------------------------------------------------
// Sampling v2: 16 lanes per (b,q,h); lane s owns sample s. ALL corner math
// (validity, clamp, flat index, corner weights) hoisted to per-lane
// precompute; the 16-iteration broadcast loop is only 8 shuffles + 4 loads
// + 8 fma -> minimal VALU between loads, loads free to pipeline.
// ---------------------------------------------------------------------------
__device__ const int   LVL_W[4]  = {100, 50, 25, 13};
__device__ const int   LVL_H[4]  = {100, 50, 25, 13};
__device__ const int   LVL_S[4]  = {0, 10000, 12500, 13125};

__global__ __launch_bounds__(256) void sample_kernel(
    const unsigned short* __restrict__ V,   // (BS*NV, 256) bf16
    const float* __restrict__ Qout,         // (BS*NQ, 384)
    const float* __restrict__ RP,           // (BS, NQ, 4, 2)
    float* __restrict__ OutS)               // (BS*NQ, 256)
{
    const int gid = blockIdx.x * 16 + (threadIdx.x >> 4);   // triple index
    const int s   = threadIdx.x & 15;                       // lane-in-group
    const int h   = gid & 7;
    const int bq  = gid >> 3;                               // b*NQ + q
    const int b   = bq / NQ;

    const float* qrow = Qout + (size_t)bq * NQOUT;

    const int l = s >> 2;
    const float ox = qrow[h * 32 + 2 * s];
    const float oy = qrow[h * 32 + 2 * s + 1];
    float logit    = qrow[256 + h * 16 + s];
    const float rpx = RP[((size_t)bq * 4 + l) * 2 + 0];
    const float rpy = RP[((size_t)bq * 4 + l) * 2 + 1];
    const int W = LVL_W[l], H = LVL_H[l], st = LVL_S[l];
    float x = rpx * (float)W + ox - 0.5f;
    float y = rpy * (float)H + oy - 0.5f;
    float fx = floorf(x), fy = floorf(y);
    float lx = x - fx, ly = y - fy;
    int x0 = (int)fx, y0 = (int)fy;
    int x1 = x0 + 1,  y1 = y0 + 1;

    // softmax over the 16 lanes of this group
    float mx = logit;
    #pragma unroll
    for (int o = 8; o; o >>= 1) mx = fmaxf(mx, __shfl_xor(mx, o, 16));
    float e = __expf(logit - mx);
    float sum = e;
    #pragma unroll
    for (int o = 8; o; o >>= 1) sum += __shfl_xor(sum, o, 16);
    const float wgt = e / sum;

    // per-lane corner precompute (hoisted out of the broadcast loop)
    const float vx0 = (x0 >= 0 && x0 < W) ? 1.f : 0.f;
    const float vx1 = (x1 >= 0 && x1 < W) ? 1.f : 0.f;
    const float vy0 = (y0 >= 0 && y0 < H) ? 1.f : 0.f;
    const float vy1 = (y1 >= 0 && y1 < H) ? 1.f : 0.f;
    const int cx0 = min(max(x0, 0), W - 1), cx1 = min(max(x1, 0), W - 1);
    const int cy0 = min(max(y0, 0), H - 1), cy1 = min(max(y1, 0), H - 1);
    float w00 = wgt * (1.f - lx) * (1.f - ly) * vx0 * vy0;
    float w10 = wgt * lx * (1.f - ly) * vx1 * vy0;
    float w01 = wgt * (1.f - lx) * ly * vx0 * vy1;
    float w11 = wgt * lx * ly * vx1 * vy1;
    int i00 = st + cy0 * W + cx0;
    int i10 = st + cy0 * W + cx1;
    int i01 = st + cy1 * W + cx0;
    int i11 = st + cy1 * W + cx1;

    const unsigned short* vb = V + ((size_t)b * NV) * 256 + h * 32 + 2 * s;
    float ax0 = 0.f, ay0 = 0.f, ax1 = 0.f, ay1 = 0.f;

    #pragma unroll
    for (int sp = 0; sp < 16; ++sp) {
        int   j00 = __shfl(i00, sp, 16), j10 = __shfl(i10, sp, 16);
        int   j01 = __shfl(i01, sp, 16), j11 = __shfl(i11, sp, 16);
        float u00 = __shfl(w00, sp, 16), u10 = __shfl(w10, sp, 16);
        float u01 = __shfl(w01, sp, 16), u11 = __shfl(w11, sp, 16);
        unsigned p00 = *(const unsigned*)(vb + (size_t)j00 * 256);
        unsigned p10 = *(const unsigned*)(vb + (size_t)j10 * 256);
        unsigned p01 = *(const unsigned*)(vb + (size_t)j01 * 256);
        unsigned p11 = *(const unsigned*)(vb + (size_t)j11 * 256);
        ax0 = fmaf(u00, bf2f((unsigned short)(p00 & 0xFFFF)), ax0);
        ay0 = fmaf(u00, bf2f((unsigned short)(p00 >> 16)), ay0);
        ax1 = fmaf(u10, bf2f((unsigned short)(p10 & 0xFFFF)), ax1);
        ay1 = fmaf(u10, bf2f((unsigned short)(p10 >> 16)), ay1);
        ax0 = fmaf(u01, bf2f((unsigned short)(p01 & 0xFFFF)), ax0);
        ay0 = fmaf(u01, bf2f((unsigned short)(p01 >> 16)), ay0);
        ax1 = fmaf(u11, bf2f((unsigned short)(p11 & 0xFFFF)), ax1);
        ay1 = fmaf(u11, bf2f((unsigned short)(p11 >> 16)), ay1);
    }
    float2* o = (float2*)(OutS + (size_t)bq * 256 + h * 32);
    o[s] = make_float2(ax0 + ax1, ay0 + ay1);
}

// ---------------------------------------------------------------------------
extern "C" void kernel_launch(void* const* d_in, const int* in_sizes, int n_in,
                              void* d_out, int out_size, void* d_ws, size_t ws_size,
                              hipStream_t stream)
{
    const float* query  = (const float*)d_in[0];
    const float* value  = (const float*)d_in[1];
    const float* rp     = (const float*)d_in[2];
    // d_in[3] spatial_shapes: static, hardcoded
    const float* W_off  = (const float*)d_in[4];
    const float* b_off  = (const float*)d_in[5];
    const float* W_attn = (const float*)d_in[6];
    const float* b_attn = (const float*)d_in[7];
    const float* W_v    = (const float*)d_in[8];
    const float* b_v    = (const float*)d_in[9];
    const float* W_out  = (const float*)d_in[10];
    const float* b_out  = (const float*)d_in[11];

    char* ws = (char*)d_ws;
    size_t off = 0;
    unsigned short* Vbf = (unsigned short*)(ws + off); off += (size_t)MV * 256 * 2;
    float* qout         = (float*)(ws + off);          off += (size_t)MQ * NQOUT * 4;
    float* outs         = (float*)(ws + off);          off += (size_t)MQ * 256 * 4;
    unsigned short* WtV = (unsigned short*)(ws + off); off += 256 * 256 * 2;
    unsigned short* WtQ = (unsigned short*)(ws + off); off += 384 * 256 * 2;
    unsigned short* WtO = (unsigned short*)(ws + off); off += 256 * 256 * 2;
    float* biasQ        = (float*)(ws + off);          off += 384 * 4;

    prep_kernel<<<384, 256, 0, stream>>>(W_v, W_off, W_attn, W_out, b_off, b_attn,
                                         WtV, WtQ, WtO, biasQ);

    // v = value @ W_v + b_v -> bf16.  512 blocks of 1024 thr, 67.6KB LDS:
    // 1 block/CU (exclusive), 16 waves/CU, R0's sharing pattern.
    gemm_ldsw16<2, 8, true, false><<<dim3(256, 2), 1024, 0, stream>>>(
        value, WtV, b_v, nullptr, Vbf, MV, 256);

    // [off | attn-logits] = query @ [W_off | W_attn] + bias.  171 blocks (R0 cfg).
    gemm_ldsw<2, 4, false, false><<<dim3(57, 3), 512, 0, stream>>>(
        query, WtQ, biasQ, nullptr, qout, MQ, NQOUT);

    sample_kernel<<<(BS * NQ * HEADS) / 16, 256, 0, stream>>>(Vbf, qout, rp, outs);

    // out = out_s @ W_out + b_out + query.  114 blocks (R0 cfg).
    gemm_ldsw<2, 4, false, true><<<dim3(57, 2), 512, 0, stream>>>(
        outs, WtO, b_out, query, (float*)d_out, MQ, 256);
}

// Round 8
// 289.459 us; speedup vs baseline: 1.4219x; 1.4219x over previous
//
#include <hip/hip_runtime.h>
#include <hip/hip_bf16.h>

// Problem constants (fixed by reference file)
#define EMBED    256
#define HEADS    8
#define LEVELS   4
#define POINTS   4
#define HEAD_DIM 32
#define BS       8
#define NQ       900
#define NV       13294          // 100*100 + 50*50 + 25*25 + 13*13
#define MV       (BS*NV)        // 106352 = 6647*16
#define MQ       (BS*NQ)        // 7200   = 450*16
#define NQOUT    384            // 256 offset cols + 128 attn cols

typedef float  f32x4  __attribute__((ext_vector_type(4)));
typedef __bf16 bf16x8 __attribute__((ext_vector_type(8)));
typedef unsigned short ushort8  __attribute__((ext_vector_type(8)));
typedef unsigned short ushort4v __attribute__((ext_vector_type(4)));

__device__ __forceinline__ unsigned short f2bf(float f) {
    unsigned u = __builtin_bit_cast(unsigned, f);
    u += 0x7FFFu + ((u >> 16) & 1u);          // RNE
    return (unsigned short)(u >> 16);
}
__device__ __forceinline__ float bf2f(unsigned short h) {
    unsigned u = ((unsigned)h) << 16;
    return __builtin_bit_cast(float, u);
}

// ---------------------------------------------------------------------------
// Prep: transpose + cast weights to bf16 (B^T layout: [n][k], k contiguous)
// ---------------------------------------------------------------------------
__global__ __launch_bounds__(256) void prep_kernel(
    const float* __restrict__ Wv,  const float* __restrict__ Woff,
    const float* __restrict__ Wattn, const float* __restrict__ Wout,
    const float* __restrict__ boff, const float* __restrict__ battn,
    unsigned short* __restrict__ WtV, unsigned short* __restrict__ WtQ,
    unsigned short* __restrict__ WtO, float* __restrict__ biasQ)
{
    int n = blockIdx.x;      // 0..383
    int k = threadIdx.x;     // 0..255
    if (n < 256) {
        WtV[n * 256 + k] = f2bf(Wv [k * 256 + n]);
        WtO[n * 256 + k] = f2bf(Wout[k * 256 + n]);
        WtQ[n * 256 + k] = f2bf(Woff[k * 256 + n]);
    } else {
        int j = n - 256;
        WtQ[n * 256 + k] = f2bf(Wattn[k * 128 + j]);
    }
    if (k == 0) biasQ[n] = (n < 256) ? boff[n] : battn[n - 256];
}

#define WLDK 264
#define AP   260   // fp32 A-tile row stride (260 mod 32 = 4 -> 2-way-free)

// ---------------------------------------------------------------------------
// V-projection GEMM, R8: COOPERATIVE TILE STAGING (canonical §5 anatomy).
// Session ladder: R0 (per-wave scattered A loads, 8 waves, clean traffic) =
// 85us @1.95 TB/s — waves ~75% stalled on per-wave per-strip load latency
// (~6.5us/strip vs ~1.5us of work). All 16-wave attempts failed: multi-block
// -> cache thrash (FETCH 3-5x, R1/R2/R3); 1024-thr single block -> hipcc
// clamps to 64 VGPR regardless of launch_bounds -> spill (R2/R4/R7).
// Fix the latency accounting instead of the wave count: per iteration all
// 512 threads cooperatively stage a 4-strip 64KB fp32 A-tile into LDS
// (1KB contiguous per wave-instruction), ONE vmcnt drain + barrier, then
// 8 waves (2 colsets x 4 parities) compute from LDS. Latency paid ~7x per
// block (once per tile) instead of ~26x per wave. Colset A-re-reads are now
// LDS hits -> the 2-way cache amplification is structurally gone.
// LDS: weights 128x264 ush (67.6KB, R0 layout) + At 4x16x260 f32 (66.5KB)
// = 134KB -> 1 block/CU exclusive (proven). Grid (256,2): y-pass-2
// L3-absorbed (R0-measured). C written in whole 256B half-rows (clean).
// ---------------------------------------------------------------------------
__global__ __launch_bounds__(512)
void gemm_v2(const float* __restrict__ A,            // [MV][256] fp32
             const unsigned short* __restrict__ Bt,  // [256][256] bf16 (B^T)
             const float* __restrict__ bias,         // [256]
             unsigned short* __restrict__ C)         // [MV][256] bf16
{
    __shared__ unsigned short Ws[128 * WLDK];        // 67584 B
    __shared__ float At[4 * 16 * AP];                // 66560 B

    const int tid = threadIdx.x;
    const int n0g = blockIdx.y * 128;

    // ---- stage weights once (barrier folded into first tile barrier) ----
    #pragma unroll
    for (int i = 0; i < 8; ++i) {
        int flat = i * 512 + tid;                    // ushort8 granule
        int row = flat >> 5, col = (flat & 31) * 8;
        *(ushort8*)&Ws[row * WLDK + col] =
            *(const ushort8*)(Bt + (size_t)(n0g + row) * 256 + col);
    }

    const int wave = tid >> 6, lane = tid & 63;
    const int colset = wave & 1, parity = wave >> 1;  // 2 colsets x 4 parities
    const int lrow = lane & 15, kq = lane >> 4;
    const int n0 = colset * 64;

    f32x4 bj[4];
    #pragma unroll
    for (int j = 0; j < 4; ++j)
        bj[j] = *(const f32x4*)(bias + n0g + n0 + j * 16 + kq * 4);

    const int NS    = MV / 16;                        // 6647
    const int chunk = (NS + gridDim.x - 1) / gridDim.x;
    const int s0b   = blockIdx.x * chunk;
    const int send  = min(NS, s0b + chunk);

    const int srow = tid >> 6;                        // staging row base 0..7
    const int gcol = (tid & 63) * 4;                  // staging col (floats)

    for (int s0 = s0b; s0 < send; s0 += 4) {
        const int ns = min(4, send - s0);             // strips this iter

        // ---- cooperative stage: 64KB tile, 1KB contiguous per wave-instr ----
        #pragma unroll
        for (int i = 0; i < 8; ++i) {
            int r = i * 8 + srow;                     // tile row 0..63
            if (r < ns * 16) {
                f32x4 v = *(const f32x4*)(A + (size_t)(s0 * 16 + r) * 256 + gcol);
                *(f32x4*)&At[r * AP + gcol] = v;
            }
        }
        __syncthreads();

        if (parity < ns) {
            const float* ar = At + (parity * 16 + lrow) * AP;
            f32x4 acc[4];
            #pragma unroll
            for (int j = 0; j < 4; ++j) acc[j] = (f32x4)0.f;
            #pragma unroll
            for (int hc = 0; hc < 8; ++hc) {          // 8 k-octets of 32
                const float* ak = ar + hc * 32 + kq * 8;
                f32x4 a0 = *(const f32x4*)ak;
                f32x4 a1 = *(const f32x4*)(ak + 4);
                ushort8 vb;
                #pragma unroll
                for (int e = 0; e < 4; ++e) {
                    vb[e]     = f2bf(a0[e]);
                    vb[4 + e] = f2bf(a1[e]);
                }
                bf16x8 vf = __builtin_bit_cast(bf16x8, vb);
                #pragma unroll
                for (int j = 0; j < 4; ++j) {
                    bf16x8 wf = *(const bf16x8*)
                        &Ws[(n0 + j * 16 + lrow) * WLDK + hc * 32 + kq * 8];
                    acc[j] = __builtin_amdgcn_mfma_f32_16x16x32_bf16(wf, vf, acc[j], 0, 0, 0);
                }
            }
            const size_t crow =
                (size_t)((s0 + parity) * 16 + lrow) * 256 + n0g + n0 + kq * 4;
            #pragma unroll
            for (int j = 0; j < 4; ++j) {
                f32x4 r = acc[j] + bj[j];
                ushort4v o;
                #pragma unroll
                for (int e = 0; e < 4; ++e) o[e] = f2bf(r[e]);
                *(ushort4v*)(C + crow + j * 16) = o;
            }
        }
        __syncthreads();                              // before tile overwrite
    }
}

// ---------------------------------------------------------------------------
// LDS-weight streaming GEMM (K=256) for the SMALL (M=7200) GEMMs — exact R0
// configuration (padded WLDK=264, 67.6KB LDS, 512thr, plain launch bounds).
// A is L2-resident at this size; R0 measured this portion fastest.
// ---------------------------------------------------------------------------
template <int COLSETS, int PAR, bool OUT_BF16, bool ADD_ID>
__global__ __launch_bounds__(COLSETS * PAR * 64)
void gemm_ldsw(const float* __restrict__ A,
               const unsigned short* __restrict__ Bt,   // [Ntot][256] bf16
               const float* __restrict__ bias,          // [Ntot]
               const float* __restrict__ Ident,         // [M][Ntot] or null
               void* __restrict__ Cv, int M, int Ntot)
{
    constexpr int NC   = COLSETS * 64;     // cols per block
    constexpr int NTHR = COLSETS * PAR * 64;
    const int n0g = blockIdx.y * NC;
    __shared__ unsigned short Ws[NC * WLDK];

    const int tid = threadIdx.x;
    #pragma unroll
    for (int i = 0; i < (NC * 32) / NTHR; ++i) {        // vec8 tiles
        int flat = i * NTHR + tid;                      // ushort8 index
        int row = flat >> 5, col = (flat & 31) * 8;     // 32 vec8 per row
        *(ushort8*)&Ws[row * WLDK + col] =
            *(const ushort8*)(Bt + (size_t)(n0g + row) * 256 + col);
    }
    __syncthreads();                                    // the only barrier

    const int wave = tid >> 6, lane = tid & 63;
    const int colset = wave % COLSETS, parity = wave / COLSETS;
    const int lrow = lane & 15, kq = lane >> 4;
    const int n0 = colset * 64;

    f32x4 bj[4];
    #pragma unroll
    for (int j = 0; j < 4; ++j)
        bj[j] = *(const f32x4*)(bias + n0g + n0 + j * 16 + kq * 4);

    const int NS    = M / 16;
    const int chunk = (NS + gridDim.x - 1) / gridDim.x;
    const int send  = min(NS, blockIdx.x * chunk + chunk);
    int s = blockIdx.x * chunk + parity;
    if (s >= send) return;

    auto loadHalf = [&](f32x4 (&b)[8], int ss, int h) {
        const float* ab = A + (size_t)(ss * 16 + lrow) * 256 + h * 128 + kq * 8;
        #pragma unroll
        for (int c = 0; c < 4; ++c) {
            b[2 * c]     = *(const f32x4*)(ab + c * 32);
            b[2 * c + 1] = *(const f32x4*)(ab + c * 32 + 4);
        }
    };
    auto computeHalf = [&](f32x4 (&b)[8], int h, f32x4 (&acc)[4]) {
        #pragma unroll
        for (int c = 0; c < 4; ++c) {
            ushort8 vb;
            #pragma unroll
            for (int e = 0; e < 4; ++e) {
                vb[e]     = f2bf(b[2 * c][e]);
                vb[4 + e] = f2bf(b[2 * c + 1][e]);
            }
            bf16x8 vf = __builtin_bit_cast(bf16x8, vb);
            #pragma unroll
            for (int j = 0; j < 4; ++j) {
                bf16x8 wf = *(const bf16x8*)
                    &Ws[(n0 + j * 16 + lrow) * WLDK + h * 128 + c * 32 + kq * 8];
                acc[j] = __builtin_amdgcn_mfma_f32_16x16x32_bf16(wf, vf, acc[j], 0, 0, 0);
            }
        }
    };

    f32x4 b0[8], b1[8];
    loadHalf(b0, s, 0);
    while (true) {
        loadHalf(b1, s, 1);
        f32x4 acc[4];
        #pragma unroll
        for (int j = 0; j < 4; ++j) acc[j] = (f32x4)0.f;
        computeHalf(b0, 0, acc);            // waits only on b0
        const int sn = s + PAR;
        const bool more = sn < send;
        if (more) loadHalf(b0, sn, 0);      // in flight during computeHalf(b1)
        computeHalf(b1, 1, acc);

        const size_t crow = (size_t)(s * 16 + lrow) * Ntot + n0g + n0 + kq * 4;
        #pragma unroll
        for (int j = 0; j < 4; ++j) {
            f32x4 r = acc[j] + bj[j];
            if (ADD_ID)
                r += *(const f32x4*)(Ident + crow + j * 16);
            if (OUT_BF16) {
                ushort4v o;
                #pragma unroll
                for (int e = 0; e < 4; ++e) o[e] = f2bf(r[e]);
                *(ushort4v*)((unsigned short*)Cv + crow + j * 16) = o;
            } else {
                *(f32x4*)((float*)Cv + crow + j * 16) = r;
            }
        }
        if (!more) break;
        s = sn;
    }
}

// ---------------------------------------------------------------------------
// Sampling v2: 16 lanes per (b,q,h); lane s owns sample s. ALL corner math
// (validity, clamp, flat index, corner weights) hoisted to per-lane
// precompute; the 16-iteration broadcast loop is only 8 shuffles + 4 loads
// + 8 fma -> minimal VALU between loads, loads free to pipeline.
// ---------------------------------------------------------------------------
__device__ const int   LVL_W[4]  = {100, 50, 25, 13};
__device__ const int   LVL_H[4]  = {100, 50, 25, 13};
__device__ const int   LVL_S[4]  = {0, 10000, 12500, 13125};

__global__ __launch_bounds__(256) void sample_kernel(
    const unsigned short* __restrict__ V,   // (BS*NV, 256) bf16
    const float* __restrict__ Qout,         // (BS*NQ, 384)
    const float* __restrict__ RP,           // (BS, NQ, 4, 2)
    float* __restrict__ OutS)               // (BS*NQ, 256)
{
    const int gid = blockIdx.x * 16 + (threadIdx.x >> 4);   // triple index
    const int s   = threadIdx.x & 15;                       // lane-in-group
    const int h   = gid & 7;
    const int bq  = gid >> 3;                               // b*NQ + q
    const int b   = bq / NQ;

    const float* qrow = Qout + (size_t)bq * NQOUT;

    const int l = s >> 2;
    const float ox = qrow[h * 32 + 2 * s];
    const float oy = qrow[h * 32 + 2 * s + 1];
    float logit    = qrow[256 + h * 16 + s];
    const float rpx = RP[((size_t)bq * 4 + l) * 2 + 0];
    const float rpy = RP[((size_t)bq * 4 + l) * 2 + 1];
    const int W = LVL_W[l], H = LVL_H[l], st = LVL_S[l];
    float x = rpx * (float)W + ox - 0.5f;
    float y = rpy * (float)H + oy - 0.5f;
    float fx = floorf(x), fy = floorf(y);
    float lx = x - fx, ly = y - fy;
    int x0 = (int)fx, y0 = (int)fy;
    int x1 = x0 + 1,  y1 = y0 + 1;

    // softmax over the 16 lanes of this group
    float mx = logit;
    #pragma unroll
    for (int o = 8; o; o >>= 1) mx = fmaxf(mx, __shfl_xor(mx, o, 16));
    float e = __expf(logit - mx);
    float sum = e;
    #pragma unroll
    for (int o = 8; o; o >>= 1) sum += __shfl_xor(sum, o, 16);
    const float wgt = e / sum;

    // per-lane corner precompute (hoisted out of the broadcast loop)
    const float vx0 = (x0 >= 0 && x0 < W) ? 1.f : 0.f;
    const float vx1 = (x1 >= 0 && x1 < W) ? 1.f : 0.f;
    const float vy0 = (y0 >= 0 && y0 < H) ? 1.f : 0.f;
    const float vy1 = (y1 >= 0 && y1 < H) ? 1.f : 0.f;
    const int cx0 = min(max(x0, 0), W - 1), cx1 = min(max(x1, 0), W - 1);
    const int cy0 = min(max(y0, 0), H - 1), cy1 = min(max(y1, 0), H - 1);
    float w00 = wgt * (1.f - lx) * (1.f - ly) * vx0 * vy0;
    float w10 = wgt * lx * (1.f - ly) * vx1 * vy0;
    float w01 = wgt * (1.f - lx) * ly * vx0 * vy1;
    float w11 = wgt * lx * ly * vx1 * vy1;
    int i00 = st + cy0 * W + cx0;
    int i10 = st + cy0 * W + cx1;
    int i01 = st + cy1 * W + cx0;
    int i11 = st + cy1 * W + cx1;

    const unsigned short* vb = V + ((size_t)b * NV) * 256 + h * 32 + 2 * s;
    float ax0 = 0.f, ay0 = 0.f, ax1 = 0.f, ay1 = 0.f;

    #pragma unroll
    for (int sp = 0; sp < 16; ++sp) {
        int   j00 = __shfl(i00, sp, 16), j10 = __shfl(i10, sp, 16);
        int   j01 = __shfl(i01, sp, 16), j11 = __shfl(i11, sp, 16);
        float u00 = __shfl(w00, sp, 16), u10 = __shfl(w10, sp, 16);
        float u01 = __shfl(w01, sp, 16), u11 = __shfl(w11, sp, 16);
        unsigned p00 = *(const unsigned*)(vb + (size_t)j00 * 256);
        unsigned p10 = *(const unsigned*)(vb + (size_t)j10 * 256);
        unsigned p01 = *(const unsigned*)(vb + (size_t)j01 * 256);
        unsigned p11 = *(const unsigned*)(vb + (size_t)j11 * 256);
        ax0 = fmaf(u00, bf2f((unsigned short)(p00 & 0xFFFF)), ax0);
        ay0 = fmaf(u00, bf2f((unsigned short)(p00 >> 16)), ay0);
        ax1 = fmaf(u10, bf2f((unsigned short)(p10 & 0xFFFF)), ax1);
        ay1 = fmaf(u10, bf2f((unsigned short)(p10 >> 16)), ay1);
        ax0 = fmaf(u01, bf2f((unsigned short)(p01 & 0xFFFF)), ax0);
        ay0 = fmaf(u01, bf2f((unsigned short)(p01 >> 16)), ay0);
        ax1 = fmaf(u11, bf2f((unsigned short)(p11 & 0xFFFF)), ax1);
        ay1 = fmaf(u11, bf2f((unsigned short)(p11 >> 16)), ay1);
    }
    float2* o = (float2*)(OutS + (size_t)bq * 256 + h * 32);
    o[s] = make_float2(ax0 + ax1, ay0 + ay1);
}

// ---------------------------------------------------------------------------
extern "C" void kernel_launch(void* const* d_in, const int* in_sizes, int n_in,
                              void* d_out, int out_size, void* d_ws, size_t ws_size,
                              hipStream_t stream)
{
    const float* query  = (const float*)d_in[0];
    const float* value  = (const float*)d_in[1];
    const float* rp     = (const float*)d_in[2];
    // d_in[3] spatial_shapes: static, hardcoded
    const float* W_off  = (const float*)d_in[4];
    const float* b_off  = (const float*)d_in[5];
    const float* W_attn = (const float*)d_in[6];
    const float* b_attn = (const float*)d_in[7];
    const float* W_v    = (const float*)d_in[8];
    const float* b_v    = (const float*)d_in[9];
    const float* W_out  = (const float*)d_in[10];
    const float* b_out  = (const float*)d_in[11];

    char* ws = (char*)d_ws;
    size_t off = 0;
    unsigned short* Vbf = (unsigned short*)(ws + off); off += (size_t)MV * 256 * 2;
    float* qout         = (float*)(ws + off);          off += (size_t)MQ * NQOUT * 4;
    float* outs         = (float*)(ws + off);          off += (size_t)MQ * 256 * 4;
    unsigned short* WtV = (unsigned short*)(ws + off); off += 256 * 256 * 2;
    unsigned short* WtQ = (unsigned short*)(ws + off); off += 384 * 256 * 2;
    unsigned short* WtO = (unsigned short*)(ws + off); off += 256 * 256 * 2;
    float* biasQ        = (float*)(ws + off);          off += 384 * 4;

    prep_kernel<<<384, 256, 0, stream>>>(W_v, W_off, W_attn, W_out, b_off, b_attn,
                                         WtV, WtQ, WtO, biasQ);

    // v = value @ W_v + b_v -> bf16.  512 blocks of 512 thr, 134KB LDS:
    // 1 block/CU exclusive, cooperative 64KB tile staging per iteration.
    gemm_v2<<<dim3(256, 2), 512, 0, stream>>>(value, WtV, b_v, Vbf);

    // [off | attn-logits] = query @ [W_off | W_attn] + bias.  171 blocks (R0 cfg).
    gemm_ldsw<2, 4, false, false><<<dim3(57, 3), 512, 0, stream>>>(
        query, WtQ, biasQ, nullptr, qout, MQ, NQOUT);

    sample_kernel<<<(BS * NQ * HEADS) / 16, 256, 0, stream>>>(Vbf, qout, rp, outs);

    // out = out_s @ W_out + b_out + query.  114 blocks (R0 cfg).
    gemm_ldsw<2, 4, false, true><<<dim3(57, 2), 512, 0, stream>>>(
        outs, WtO, b_out, query, (float*)d_out, MQ, 256);
}